// Round 9
// baseline (92.344 us; speedup 1.0000x reference)
//
#include <hip/hip_runtime.h>

#define MDIM 4096
#define KDIM 2048
#define UDIM 1024
#define CMOFF (MDIM * UDIM)
#define THREADS 512

typedef __bf16 bfrag __attribute__((ext_vector_type(8)));
typedef float f32x16 __attribute__((ext_vector_type(16)));

#define GLDS(gsrc, ldst)                                                                  \
  __builtin_amdgcn_global_load_lds((const __attribute__((address_space(1))) void*)(gsrc), \
                                   (__attribute__((address_space(3))) void*)(ldst), 16, 0, 0)

__device__ __forceinline__ unsigned short f2bf(float x) {
  unsigned int u = __float_as_uint(x);
  unsigned int r = (u + 0x7fffu + ((u >> 16) & 1u)) >> 16;
  return (unsigned short)r;
}

__device__ __forceinline__ float fast_sigmoid(float x) { return 1.f / (1.f + __expf(-x)); }

__device__ __forceinline__ float fast_tanh(float x) {
  float ax = fabsf(x);
  float e = __expf(-2.f * ax);
  float r = (1.f - e) / (1.f + e);
  return copysignf(r, x);
}

// ---------------------------------------------------------------------------
// Packed operand layouts (16B granules, exactly the LDS staging image):
//   Apk[P(16)][S(32)][g(8)][n(256)] : granule = A[row P*256+n][k S*64+g*8 ..+7]
//   Bpk[bn(16)][S(32)][g(8)][n'(256)]: n' = wc*128 + q*32 + cl  <->
//        gate q, unit u = bn*64 + wc*32 + cl ; granule = W_q[k S*64+g*8..+7][u]
// GLDS staging (G = c*512+tid consecutive) is then 1KB/wave coalesced, and all
// fragment ds_read_b128 are 32-lane-contiguous 512B blocks (uniform banks).
// ---------------------------------------------------------------------------

// A = [hidden | inputs] -> bf16 granule-packed
__global__ void pack_x(const float* __restrict__ hidden, const float* __restrict__ inputs,
                       unsigned short* __restrict__ Apk) {
  __shared__ uint4 t4[2048];  // granule-linear [g(8)][n(256)]
  const int P = blockIdx.x;   // m-panel
  const int S = blockIdx.y;   // k-step (64 wide)
  const int tid = threadIdx.x;  // 256
  const size_t m = (size_t)P * 256 + tid;
  const float* src = (S < 16) ? (hidden + m * 1024 + S * 64) : (inputs + m * 1024 + (S - 16) * 64);
  const float4* s4 = (const float4*)src;
#pragma unroll
  for (int j = 0; j < 8; ++j) {  // granule j: k j*8..+7
    float4 v0 = s4[2 * j], v1 = s4[2 * j + 1];
    uint4 g;
    g.x = (unsigned)f2bf(v0.x) | ((unsigned)f2bf(v0.y) << 16);
    g.y = (unsigned)f2bf(v0.z) | ((unsigned)f2bf(v0.w) << 16);
    g.z = (unsigned)f2bf(v1.x) | ((unsigned)f2bf(v1.y) << 16);
    g.w = (unsigned)f2bf(v1.z) | ((unsigned)f2bf(v1.w) << 16);
    t4[j * 256 + tid] = g;  // lanes contiguous 16B -> conflict-free
  }
  __syncthreads();
  uint4* dst = (uint4*)(Apk + ((size_t)P * 32 + S) * 16384);
#pragma unroll
  for (int c = 0; c < 8; ++c) dst[c * 256 + tid] = t4[c * 256 + tid];  // coalesced
}

// W_f/i/c/o -> bf16 granule-packed (transpose to n'-major)
__global__ void pack_w(const float* __restrict__ Wf, const float* __restrict__ Wi,
                       const float* __restrict__ Wc, const float* __restrict__ Wo,
                       unsigned short* __restrict__ Bpk) {
  __shared__ unsigned short t1[4][64][64];  // [gate][k-in-step][u-local]
  const int bn = blockIdx.x;
  const int S = blockIdx.y;
  const int tid = threadIdx.x;  // 256
  const int q = tid >> 6, kk = tid & 63;
  const float* W = (q == 0) ? Wf : (q == 1) ? Wi : (q == 2) ? Wc : Wo;
  const float* src = W + (size_t)(S * 64 + kk) * UDIM + bn * 64;
#pragma unroll
  for (int i = 0; i < 16; ++i) {  // 64 u, 4 at a time
    float4 v = ((const float4*)src)[i];
    t1[q][kk][i * 4 + 0] = f2bf(v.x);
    t1[q][kk][i * 4 + 1] = f2bf(v.y);
    t1[q][kk][i * 4 + 2] = f2bf(v.z);
    t1[q][kk][i * 4 + 3] = f2bf(v.w);
  }
  __syncthreads();
  // granule (g=c, n'=tid): elems t1[q'][c*8+e][ul], q'=(tid>>5)&3, ul=(tid>>7)*32+(tid&31)
  const int qp = (tid >> 5) & 3;
  const int ul = ((tid >> 7) << 5) + (tid & 31);
  uint4* dst = (uint4*)(Bpk + ((size_t)bn * 32 + S) * 16384);
#pragma unroll
  for (int c = 0; c < 8; ++c) {
    const unsigned short* p = &t1[qp][c * 8][ul];
    uint4 g;
    g.x = (unsigned)p[0] | ((unsigned)p[64] << 16);
    g.y = (unsigned)p[128] | ((unsigned)p[192] << 16);
    g.z = (unsigned)p[256] | ((unsigned)p[320] << 16);
    g.w = (unsigned)p[384] | ((unsigned)p[448] << 16);
    dst[c * 256 + tid] = g;
  }
}

// Fused 4-gate GEMM + LSTM epilogue, 32x32x16 MFMA, sync-minimal.
// 256x256 tile, BK=64, 2 LDS dbufs (128 KiB), 8 waves 4M x 2N (wave = 64x128).
// ONE vmcnt(0) + ONE barrier per K-step:
//   [vmcnt(0): own GLDS for ring R (issued a full step earlier -> free pass);
//    barrier: publishes all waves' stage-R + guarantees all ring R^1 readers of
//    step S-1 are done (their reads were consumed by lgkm-waited MFMAs before
//    they arrived here); then stage ring R^1 for step S+1 + compute ring R.]
// All LDS traffic (GLDS writes, ds_read_b128 frags) is 32-lane-contiguous ->
// uniform bank load, conflict-free by construction. No swizzle math.
__global__ __launch_bounds__(THREADS, 2) void lstm_gemm(
    const unsigned short* __restrict__ Apk, const unsigned short* __restrict__ Bpk,
    const float* __restrict__ bf_, const float* __restrict__ bi_,
    const float* __restrict__ bc_, const float* __restrict__ bo_,
    const float* __restrict__ cell, float* __restrict__ out) {
  extern __shared__ __bf16 lds[];  // 2 rings x (A 16384 + B 16384 elems) = 128 KiB

  const int tid = threadIdx.x;
  const int lane = tid & 63;
  const int wid = tid >> 6;
  const int wr = wid >> 1;  // M quarter (64 rows)
  const int wc = wid & 1;   // N half (128 cols)
  const int cl = lane & 31;
  const int hb = lane >> 5;  // k-granule half

  // bijective XCD swizzle over exactly 256 workgroups (1 per CU)
  const int wg = blockIdx.x;
  const int swz = (wg & 7) * 32 + (wg >> 3);
  const int P = swz >> 4;    // m-panel
  const int m0 = P * 256;
  const int bn = swz & 15;   // 64-unit block

  // staging sources: granule-linear, G = c*512 + tid
  const unsigned short* aP = Apk + (size_t)P * 524288 + (size_t)tid * 8;
  const unsigned short* bP = Bpk + (size_t)bn * 524288 + (size_t)tid * 8;

  f32x16 acc[2][4];
#pragma unroll
  for (int mf = 0; mf < 2; ++mf)
#pragma unroll
    for (int nf = 0; nf < 4; ++nf)
#pragma unroll
      for (int j = 0; j < 16; ++j) acc[mf][nf][j] = 0.f;

  // fragment read bases (elems): A: (ks*2+hb)*2048 + row*8 ; row = wr*64+mf*32+cl
  const int aBase = hb * 2048 + (wr * 64 + cl) * 8;
  const int bBase = 16384 + hb * 2048 + (wc * 128 + cl) * 8;

#define STAGE(RING)                                                               \
  do {                                                                            \
    _Pragma("unroll") for (int c = 0; c < 4; ++c)                                 \
        GLDS(aP + c * 4096, lds + (RING) * 32768 + c * 4096 + tid * 8);           \
    _Pragma("unroll") for (int c = 0; c < 4; ++c)                                 \
        GLDS(bP + c * 4096, lds + (RING) * 32768 + 16384 + c * 4096 + tid * 8);   \
    aP += 16384;                                                                  \
    bP += 16384;                                                                  \
  } while (0)

#define STEP_BODY(RING, DO_STAGE)                                                     \
  do {                                                                                \
    asm volatile("s_waitcnt vmcnt(0)" ::: "memory");                                  \
    __builtin_amdgcn_s_barrier();                                                     \
    __builtin_amdgcn_sched_barrier(0);                                                \
    if (DO_STAGE) STAGE((RING) ^ 1);                                                  \
    const __bf16* apl = lds + (RING) * 32768 + aBase;                                 \
    const __bf16* bpl = lds + (RING) * 32768 + bBase;                                 \
    _Pragma("unroll") for (int ks = 0; ks < 4; ++ks) {                                \
      bfrag a0 = *(const bfrag*)(apl + ks * 4096);                                    \
      bfrag a1 = *(const bfrag*)(apl + ks * 4096 + 256);                              \
      bfrag b0 = *(const bfrag*)(bpl + ks * 4096);                                    \
      bfrag b1 = *(const bfrag*)(bpl + ks * 4096 + 256);                              \
      bfrag b2 = *(const bfrag*)(bpl + ks * 4096 + 512);                              \
      bfrag b3 = *(const bfrag*)(bpl + ks * 4096 + 768);                              \
      __builtin_amdgcn_s_setprio(1);                                                  \
      acc[0][0] = __builtin_amdgcn_mfma_f32_32x32x16_bf16(a0, b0, acc[0][0], 0, 0, 0);\
      acc[0][1] = __builtin_amdgcn_mfma_f32_32x32x16_bf16(a0, b1, acc[0][1], 0, 0, 0);\
      acc[0][2] = __builtin_amdgcn_mfma_f32_32x32x16_bf16(a0, b2, acc[0][2], 0, 0, 0);\
      acc[0][3] = __builtin_amdgcn_mfma_f32_32x32x16_bf16(a0, b3, acc[0][3], 0, 0, 0);\
      acc[1][0] = __builtin_amdgcn_mfma_f32_32x32x16_bf16(a1, b0, acc[1][0], 0, 0, 0);\
      acc[1][1] = __builtin_amdgcn_mfma_f32_32x32x16_bf16(a1, b1, acc[1][1], 0, 0, 0);\
      acc[1][2] = __builtin_amdgcn_mfma_f32_32x32x16_bf16(a1, b2, acc[1][2], 0, 0, 0);\
      acc[1][3] = __builtin_amdgcn_mfma_f32_32x32x16_bf16(a1, b3, acc[1][3], 0, 0, 0);\
      __builtin_amdgcn_s_setprio(0);                                                  \
    }                                                                                 \
  } while (0)

  // prologue: stage step 0 into ring 0
  STAGE(0);

  for (int it = 0; it < 15; ++it) {  // steps 0..29
    STEP_BODY(0, 1);
    STEP_BODY(1, 1);
  }
  STEP_BODY(0, 1);  // step 30 (stages step 31 into ring 1)
  STEP_BODY(1, 0);  // step 31

  // ---- epilogue: lane-local. nf == gate; unit u = bn*64 + wc*32 + cl ----
  const int u = bn * 64 + wc * 32 + cl;
  const float fb = bf_[u], ib = bi_[u], cb = bc_[u], ob = bo_[u];
  const int rbase = m0 + wr * 64 + 4 * hb;
#pragma unroll
  for (int mf = 0; mf < 2; ++mf) {
#pragma unroll
    for (int r = 0; r < 16; ++r) {
      const int m = rbase + mf * 32 + (r & 3) + 8 * (r >> 2);
      float pf = acc[mf][0][r] + fb;
      float pi = acc[mf][1][r] + ib;
      float pc = acc[mf][2][r] + cb;
      float po = acc[mf][3][r] + ob;
      float fg = fast_sigmoid(pf);
      float ig = fast_sigmoid(pi);
      float cc = fast_tanh(pc);
      float og = fast_sigmoid(po);
      float cold = cell[(size_t)m * UDIM + u];
      float cnew = fg * cold + ig * cc;
      out[(size_t)m * UDIM + u] = og * fast_tanh(cnew);
      out[CMOFF + (size_t)m * UDIM + u] = cnew;
    }
  }
}

extern "C" void kernel_launch(void* const* d_in, const int* in_sizes, int n_in,
                              void* d_out, int out_size, void* d_ws, size_t ws_size,
                              hipStream_t stream) {
  const float* inputs = (const float*)d_in[0];
  const float* hidden = (const float*)d_in[1];
  const float* cell = (const float*)d_in[2];
  const float* Wf = (const float*)d_in[3];
  const float* bf = (const float*)d_in[4];
  const float* Wi = (const float*)d_in[5];
  const float* bi = (const float*)d_in[6];
  const float* Wc = (const float*)d_in[7];
  const float* bc = (const float*)d_in[8];
  const float* Wo = (const float*)d_in[9];
  const float* bo = (const float*)d_in[10];
  float* out = (float*)d_out;

  unsigned short* Apk = (unsigned short*)d_ws;      // 16 MB granule-packed A
  unsigned short* Bpk = Apk + (size_t)MDIM * KDIM;  // 16 MB granule-packed W^T

  pack_x<<<dim3(16, 32), 256, 0, stream>>>(hidden, inputs, Apk);
  pack_w<<<dim3(16, 32), 256, 0, stream>>>(Wf, Wi, Wc, Wo, Bpk);
  lstm_gemm<<<dim3(256), dim3(THREADS), 131072, stream>>>(Apk, Bpk, bf, bi, bc, bo, cell, out);
}